// Round 1
// baseline (1838.480 us; speedup 1.0000x reference)
//
#include <hip/hip_runtime.h>

#define TLEN 1024
#define CDIM 256
#define NHEAD 4
#define HD 64
#define WIN_ 128
#define PADL 63
#define LWIN 1023
#define TPAD 1150
#define KPAD 68      // LDS row stride (floats): 16B-aligned rows, breaks stride-64 bank conflicts
#define SW 16        // windows per strip in attention kernel

__device__ __forceinline__ int prow(int v, int t) {
  // row index into P (1150 x 768) for variant v at padded position t.
  // Pad rows [0,63) and [1087,1150) are zero for BOTH variants (P memset to 0).
  if (v == 0) return t;
  if (t < PADL || t >= PADL + TLEN) return t;
  int s = t - PADL;
  s = (s + (TLEN - 64)) & (TLEN - 1);   // roll(x, +64): x_shift[s] = x[(s-64) mod 1024]
  return PADL + s;
}

__device__ __forceinline__ float hannf(int j) {
  return 0.5f * (1.0f - __cosf(6.283185307179586f * (float)j / 127.0f));
}

__device__ __forceinline__ float countf(int t) {
  int lo = t - 127; if (lo < 0) lo = 0;
  int hi = t;       if (hi > LWIN - 1) hi = LWIN - 1;
  return (float)(hi - lo + 1);
}

// ---------------- LayerNorm: ln[s][c] = (x-mu)*rsqrt(var+1e-5)*g + b ----------------
__global__ void k_ln(const float* __restrict__ x, const float* __restrict__ g,
                     const float* __restrict__ b, float* __restrict__ ln) {
  int wv = threadIdx.x >> 6, lane = threadIdx.x & 63;
  int r = blockIdx.x * 4 + wv;
  float4 v = ((const float4*)(x + (size_t)r * CDIM))[lane];
  float s = v.x + v.y + v.z + v.w;
  float q = v.x * v.x + v.y * v.y + v.z * v.z + v.w * v.w;
  #pragma unroll
  for (int m = 32; m >= 1; m >>= 1) { s += __shfl_xor(s, m); q += __shfl_xor(q, m); }
  float mu = s * (1.0f / 256.0f);
  float var = q * (1.0f / 256.0f) - mu * mu;
  float rs = rsqrtf(var + 1e-5f);
  float4 gg = ((const float4*)g)[lane];
  float4 bb = ((const float4*)b)[lane];
  float4 o;
  o.x = (v.x - mu) * rs * gg.x + bb.x;
  o.y = (v.y - mu) * rs * gg.y + bb.y;
  o.z = (v.z - mu) * rs * gg.z + bb.z;
  o.w = (v.w - mu) * rs * gg.w + bb.w;
  ((float4*)(ln + (size_t)r * CDIM))[lane] = o;
}

// ---------------- P[63+s][e] = sum_c ln[s][c] * in_proj_w[e][c] ----------------
__global__ void k_proj(const float* __restrict__ ln, const float* __restrict__ W,
                       float* __restrict__ P) {
  __shared__ float lnt[16][257];
  __shared__ float Wt[256][65];
  int tid = threadIdx.x;
  int s0 = blockIdx.x * 16;
  int e0 = blockIdx.y * 256;
  for (int idx = tid; idx < 16 * 256; idx += 256)
    lnt[idx >> 8][idx & 255] = ln[(size_t)(s0 + (idx >> 8)) * CDIM + (idx & 255)];
  float acc[16];
  #pragma unroll
  for (int r = 0; r < 16; ++r) acc[r] = 0.0f;
  for (int kk = 0; kk < 4; ++kk) {
    __syncthreads();
    for (int idx = tid; idx < 256 * 64; idx += 256)
      Wt[idx >> 6][idx & 63] = W[(size_t)(e0 + (idx >> 6)) * CDIM + kk * 64 + (idx & 63)];
    __syncthreads();
    for (int c = 0; c < 64; ++c) {
      float wv = Wt[tid][c];
      #pragma unroll
      for (int r = 0; r < 16; ++r) acc[r] += lnt[r][kk * 64 + c] * wv;
    }
  }
  #pragma unroll
  for (int r = 0; r < 16; ++r)
    P[(size_t)(PADL + s0 + r) * 768 + e0 + tid] = acc[r];
}

// ---------------- Mt[c][e] = (proj_w @ out_w)[e][c]; vbv[e] = proj_w[e]·out_b ----------------
__global__ void k_mmat(const float* __restrict__ pw, const float* __restrict__ ow,
                       const float* __restrict__ ob, float* __restrict__ Mt,
                       float* __restrict__ vbv) {
  __shared__ float pr[256];
  __shared__ float red[256];
  int e = blockIdx.x, tid = threadIdx.x;
  pr[tid] = pw[(size_t)e * CDIM + tid];
  __syncthreads();
  float acc = 0.0f;
  for (int m = 0; m < 256; ++m) acc += pr[m] * ow[(size_t)m * CDIM + tid];
  Mt[(size_t)tid * CDIM + e] = acc;   // transposed store so k_comb reads coalesce
  red[tid] = pr[tid] * ob[tid];
  __syncthreads();
  for (int s = 128; s > 0; s >>= 1) { if (tid < s) red[tid] += red[tid + s]; __syncthreads(); }
  if (tid == 0) vbv[e] = red[0];
}

// ---------------- Attention: strip of SW windows, one head, one variant per block ----------------
__launch_bounds__(256, 1)
__global__ void k_attn(const float* __restrict__ P, const float* __restrict__ ipb,
                       float* __restrict__ accg) {
  __shared__ float qb[WIN_][KPAD];
  __shared__ float kb[WIN_][KPAD];
  __shared__ float vb[WIN_][KPAD];
  __shared__ float accs[SW - 1 + WIN_][KPAD];

  const int strip = blockIdx.x;
  const int h = blockIdx.y;
  const int v = blockIdx.z;
  const int l0 = strip * SW;
  const int nw = (SW < LWIN - l0) ? SW : (LWIN - l0);
  const int tid = threadIdx.x;
  const int r = tid >> 1;        // q-row owned by this thread pair
  const int half = tid & 1;      // which 64 columns of the 128
  const int cbase = half * 64;

  for (int i = tid; i < (SW - 1 + WIN_) * KPAD; i += 256) (&accs[0][0])[i] = 0.0f;

  #pragma unroll 1
  for (int w = 0; w < nw; ++w) {
    const int l = l0 + w;
    __syncthreads();
    // stage Q,K,V with hann + bias applied (pad rows of P are zero -> q=bias there, matching ref)
    for (int i = tid; i < WIN_ * HD; i += 256) {
      int j = i >> 6, dd = i & 63;
      int row = prow(v, l + j);
      float hj = hannf(j);
      const float* pr = P + (size_t)row * 768 + h * 64 + dd;
      qb[j][dd] = hj * pr[0]   + ipb[h * 64 + dd];
      kb[j][dd] = hj * pr[256] + ipb[256 + h * 64 + dd];
      vb[j][dd] = hj * pr[512] + ipb[512 + h * 64 + dd];
    }
    __syncthreads();

    // scores for row r, columns [cbase, cbase+64)
    float sc[64];
    #pragma unroll
    for (int c = 0; c < 64; ++c) sc[c] = 0.0f;
    const float4* qrow = (const float4*)&qb[r][0];
    for (int i4 = 0; i4 < 16; ++i4) {
      float4 qv = qrow[i4];
      #pragma unroll
      for (int c = 0; c < 64; ++c) {
        float4 kv = ((const float4*)&kb[cbase + c][0])[i4];
        sc[c] += qv.x * kv.x + qv.y * kv.y + qv.z * kv.z + qv.w * kv.w;
      }
    }
    #pragma unroll
    for (int c = 0; c < 64; ++c) sc[c] *= 0.125f;

    // softmax across the 128 columns (pair via shfl_xor 1)
    float m = -3.0e38f;
    #pragma unroll
    for (int c = 0; c < 64; ++c) m = fmaxf(m, sc[c]);
    m = fmaxf(m, __shfl_xor(m, 1));
    float ssum = 0.0f;
    #pragma unroll
    for (int c = 0; c < 64; ++c) { float e = __expf(sc[c] - m); sc[c] = e; ssum += e; }
    ssum += __shfl_xor(ssum, 1);
    float inv = 1.0f / ssum;
    #pragma unroll
    for (int c = 0; c < 64; ++c) sc[c] *= inv;

    // O = A @ V (partial over this half's 64 columns)
    float4 o4[16];
    #pragma unroll
    for (int d4 = 0; d4 < 16; ++d4) o4[d4] = make_float4(0.f, 0.f, 0.f, 0.f);
    #pragma unroll
    for (int c = 0; c < 64; ++c) {
      float a = sc[c];
      const float4* vrow = (const float4*)&vb[cbase + c][0];
      #pragma unroll
      for (int d4 = 0; d4 < 16; ++d4) {
        float4 vv = vrow[d4];
        o4[d4].x += a * vv.x; o4[d4].y += a * vv.y;
        o4[d4].z += a * vv.z; o4[d4].w += a * vv.w;
      }
    }
    #pragma unroll
    for (int d4 = 0; d4 < 16; ++d4) {
      o4[d4].x += __shfl_xor(o4[d4].x, 1);
      o4[d4].y += __shfl_xor(o4[d4].y, 1);
      o4[d4].z += __shfl_xor(o4[d4].z, 1);
      o4[d4].w += __shfl_xor(o4[d4].w, 1);
    }
    const int pos = w + r;
    float4* arow = (float4*)&accs[pos][0];
    const int db = half * 8;   // even lane: dd 0..31, odd lane: dd 32..63
    #pragma unroll
    for (int d4 = 0; d4 < 8; ++d4) {
      float4 cur = arow[db + d4];
      float4 add = o4[db + d4];
      cur.x += add.x; cur.y += add.y; cur.z += add.z; cur.w += add.w;
      arow[db + d4] = cur;
    }
  }

  __syncthreads();
  const int span = nw - 1 + WIN_;
  float* av = accg + (size_t)v * TPAD * CDIM;
  for (int i = tid; i < span * HD; i += 256) {
    int p = i >> 6, dd = i & 63;
    atomicAdd(&av[(size_t)(l0 + p) * CDIM + h * 64 + dd], accs[p][dd]);
  }
}

// ---------------- combine variants, divide by counts, apply merged (proj_w@out_w) ----------------
__global__ void k_comb(const float* __restrict__ accg, const float* __restrict__ Mt,
                       const float* __restrict__ vbv, const float* __restrict__ pb,
                       float* __restrict__ z, float* __restrict__ msum) {
  __shared__ float ut[16][257];
  __shared__ float bsc[16];
  int tid = threadIdx.x;
  int s0 = blockIdx.x * 16;
  for (int idx = tid; idx < 16 * 256; idx += 256) {
    int rr = idx >> 8, c = idx & 255;
    int s = s0 + rr;
    int t0 = PADL + s;
    float c0 = countf(t0);
    int s1 = (s + 64) & (TLEN - 1);     // undo roll(-64) on shifted output
    int t1 = PADL + s1;
    float c1 = countf(t1);
    float a0 = accg[(size_t)t0 * CDIM + c];
    float a1 = accg[(size_t)TPAD * CDIM + (size_t)t1 * CDIM + c];
    ut[rr][c] = 0.5f * (a0 / (c0 + 1e-6f) + a1 / (c1 + 1e-6f));
  }
  if (tid < 16) {
    int s = s0 + tid;
    float c0 = countf(PADL + s);
    float c1 = countf(PADL + ((s + 64) & (TLEN - 1)));
    bsc[tid] = 0.5f * (c0 / (c0 + 1e-6f) + c1 / (c1 + 1e-6f));
  }
  __syncthreads();
  float zr[16];
  #pragma unroll
  for (int rr = 0; rr < 16; ++rr) zr[rr] = 0.0f;
  for (int c = 0; c < 256; ++c) {
    float mv = Mt[(size_t)c * CDIM + tid];
    #pragma unroll
    for (int rr = 0; rr < 16; ++rr) zr[rr] += ut[rr][c] * mv;
  }
  float vbe = vbv[tid], pbe = pb[tid];
  float part = 0.0f;
  #pragma unroll
  for (int rr = 0; rr < 16; ++rr) {
    float val = zr[rr] + bsc[rr] * vbe + pbe;
    z[(size_t)(s0 + rr) * CDIM + tid] = val;
    part += val;
  }
  atomicAdd(&msum[tid], part);
}

// ---------------- SE gate ----------------
__global__ void k_se(const float* __restrict__ msum, const float* __restrict__ w1,
                     const float* __restrict__ w2, float* __restrict__ gate) {
  __shared__ float sm[256];
  __shared__ float s1[16];
  int tid = threadIdx.x;
  sm[tid] = msum[tid] * (1.0f / 1024.0f);
  __syncthreads();
  if (tid < 16) {
    float a = 0.0f;
    for (int e = 0; e < 256; ++e) a += sm[e] * w1[(size_t)tid * 256 + e];
    s1[tid] = fmaxf(a, 0.0f);
  }
  __syncthreads();
  float gacc = 0.0f;
  #pragma unroll
  for (int i = 0; i < 16; ++i) gacc += s1[i] * w2[(size_t)tid * 16 + i];
  gate[tid] = 1.0f / (1.0f + __expf(-gacc));
}

// ---------------- out = x + z * gate ----------------
__global__ void k_final(const float* __restrict__ x, const float* __restrict__ z,
                        const float* __restrict__ gate, float* __restrict__ out) {
  int i = blockIdx.x * 256 + threadIdx.x;
  float4 xv = ((const float4*)x)[i];
  float4 zv = ((const float4*)z)[i];
  float4 gv = ((const float4*)gate)[i & 63];
  float4 o;
  o.x = xv.x + zv.x * gv.x;
  o.y = xv.y + zv.y * gv.y;
  o.z = xv.z + zv.z * gv.z;
  o.w = xv.w + zv.w * gv.w;
  ((float4*)out)[i] = o;
}

extern "C" void kernel_launch(void* const* d_in, const int* in_sizes, int n_in,
                              void* d_out, int out_size, void* d_ws, size_t ws_size,
                              hipStream_t stream) {
  const float* x   = (const float*)d_in[0];
  const float* lng = (const float*)d_in[1];
  const float* lnb = (const float*)d_in[2];
  const float* ipw = (const float*)d_in[3];
  const float* ipb = (const float*)d_in[4];
  const float* ow  = (const float*)d_in[5];
  const float* ob  = (const float*)d_in[6];
  const float* pw  = (const float*)d_in[7];
  const float* pb  = (const float*)d_in[8];
  const float* w1  = (const float*)d_in[9];
  const float* w2  = (const float*)d_in[10];
  float* out = (float*)d_out;

  float* ws   = (float*)d_ws;
  float* ln   = ws;                       // 1024*256
  float* P    = ln + TLEN * CDIM;         // 1150*768
  float* accg = P + TPAD * 768;           // 2*1150*256
  float* Mt   = accg + 2 * TPAD * CDIM;   // 256*256
  float* vbv  = Mt + CDIM * CDIM;         // 256
  float* z    = vbv + CDIM;               // 1024*256
  float* msum = z + TLEN * CDIM;          // 256
  // gate right after msum
  float* gate = msum + CDIM;              // 256

  hipMemsetAsync(P, 0, (size_t)TPAD * 768 * sizeof(float), stream);
  hipMemsetAsync(accg, 0, (size_t)2 * TPAD * CDIM * sizeof(float), stream);
  hipMemsetAsync(msum, 0, CDIM * sizeof(float), stream);

  k_ln<<<dim3(TLEN / 4), dim3(256), 0, stream>>>(x, lng, lnb, ln);
  k_proj<<<dim3(64, 3), dim3(256), 0, stream>>>(ln, ipw, P);
  k_mmat<<<dim3(256), dim3(256), 0, stream>>>(pw, ow, ob, Mt, vbv);
  k_attn<<<dim3(64, NHEAD, 2), dim3(256), 0, stream>>>(P, ipb, accg);
  k_comb<<<dim3(64), dim3(256), 0, stream>>>(accg, Mt, vbv, pb, z, msum);
  k_se<<<dim3(1), dim3(256), 0, stream>>>(msum, w1, w2, gate);
  k_final<<<dim3(256), dim3(256), 0, stream>>>(x, z, gate, out);
}

// Round 2
// 346.457 us; speedup vs baseline: 5.3065x; 5.3065x over previous
//
#include <hip/hip_runtime.h>

#define TLEN 1024
#define CDIM 256
#define NHEAD 4
#define HD 64
#define WIN_ 128
#define PADL 63
#define LWIN 1023
#define TPAD 1150
#define SW 16        // windows per strip in attention kernel

typedef __attribute__((ext_vector_type(8))) short bf16x8;
typedef __attribute__((ext_vector_type(4))) float f32x4;

__device__ __forceinline__ int prow(int v, int t) {
  if (v == 0) return t;
  if (t < PADL || t >= PADL + TLEN) return t;
  int s = t - PADL;
  s = (s + (TLEN - 64)) & (TLEN - 1);   // roll(x, +64)
  return PADL + s;
}

__device__ __forceinline__ float hannf(int j) {
  return 0.5f * (1.0f - __cosf(6.283185307179586f * (float)j / 127.0f));
}

__device__ __forceinline__ float countf(int t) {
  int lo = t - 127; if (lo < 0) lo = 0;
  int hi = t;       if (hi > LWIN - 1) hi = LWIN - 1;
  return (float)(hi - lo + 1);
}

__device__ __forceinline__ unsigned short bfr(float f) {  // fp32 -> bf16 RTNE
  unsigned int u = __float_as_uint(f);
  u += 0x7FFFu + ((u >> 16) & 1u);
  return (unsigned short)(u >> 16);
}
__device__ __forceinline__ unsigned int pk2(float a, float b) {
  return (unsigned int)bfr(a) | ((unsigned int)bfr(b) << 16);
}
__device__ __forceinline__ float bflo(unsigned int u) { return __uint_as_float(u << 16); }
__device__ __forceinline__ float bfhi(unsigned int u) { return __uint_as_float(u & 0xFFFF0000u); }

// ---------------- LayerNorm ----------------
__global__ void k_ln(const float* __restrict__ x, const float* __restrict__ g,
                     const float* __restrict__ b, float* __restrict__ ln) {
  int wv = threadIdx.x >> 6, lane = threadIdx.x & 63;
  int r = blockIdx.x * 4 + wv;
  float4 v = ((const float4*)(x + (size_t)r * CDIM))[lane];
  float s = v.x + v.y + v.z + v.w;
  float q = v.x * v.x + v.y * v.y + v.z * v.z + v.w * v.w;
  #pragma unroll
  for (int m = 32; m >= 1; m >>= 1) { s += __shfl_xor(s, m); q += __shfl_xor(q, m); }
  float mu = s * (1.0f / 256.0f);
  float var = q * (1.0f / 256.0f) - mu * mu;
  float rs = rsqrtf(var + 1e-5f);
  float4 gg = ((const float4*)g)[lane];
  float4 bb = ((const float4*)b)[lane];
  float4 o;
  o.x = (v.x - mu) * rs * gg.x + bb.x;
  o.y = (v.y - mu) * rs * gg.y + bb.y;
  o.z = (v.z - mu) * rs * gg.z + bb.z;
  o.w = (v.w - mu) * rs * gg.w + bb.w;
  ((float4*)(ln + (size_t)r * CDIM))[lane] = o;
}

// ---------------- P projection (bf16 out) ----------------
__global__ void k_proj(const float* __restrict__ ln, const float* __restrict__ W,
                       unsigned short* __restrict__ Pbf) {
  __shared__ float lnt[16][257];
  __shared__ float Wt[256][65];
  int tid = threadIdx.x;
  int s0 = blockIdx.x * 16;
  int e0 = blockIdx.y * 256;
  for (int idx = tid; idx < 16 * 256; idx += 256)
    lnt[idx >> 8][idx & 255] = ln[(size_t)(s0 + (idx >> 8)) * CDIM + (idx & 255)];
  float acc[16];
  #pragma unroll
  for (int r = 0; r < 16; ++r) acc[r] = 0.0f;
  for (int kk = 0; kk < 4; ++kk) {
    __syncthreads();
    for (int idx = tid; idx < 256 * 64; idx += 256)
      Wt[idx >> 6][idx & 63] = W[(size_t)(e0 + (idx >> 6)) * CDIM + kk * 64 + (idx & 63)];
    __syncthreads();
    for (int c = 0; c < 64; ++c) {
      float wv = Wt[tid][c];
      #pragma unroll
      for (int r = 0; r < 16; ++r) acc[r] += lnt[r][kk * 64 + c] * wv;
    }
  }
  #pragma unroll
  for (int r = 0; r < 16; ++r)
    Pbf[(size_t)(PADL + s0 + r) * 768 + e0 + tid] = bfr(acc[r]);
}

// ---------------- merged out/proj matrices ----------------
__global__ void k_mmat(const float* __restrict__ pw, const float* __restrict__ ow,
                       const float* __restrict__ ob, float* __restrict__ Mt,
                       float* __restrict__ vbv) {
  __shared__ float pr[256];
  __shared__ float red[256];
  int e = blockIdx.x, tid = threadIdx.x;
  pr[tid] = pw[(size_t)e * CDIM + tid];
  __syncthreads();
  float acc = 0.0f;
  for (int m = 0; m < 256; ++m) acc += pr[m] * ow[(size_t)m * CDIM + tid];
  Mt[(size_t)tid * CDIM + e] = acc;
  red[tid] = pr[tid] * ob[tid];
  __syncthreads();
  for (int s = 128; s > 0; s >>= 1) { if (tid < s) red[tid] += red[tid + s]; __syncthreads(); }
  if (tid == 0) vbv[e] = red[0];
}

// ---------------- MFMA attention ----------------
__launch_bounds__(256, 1)
__global__ void k_attn(const unsigned short* __restrict__ Pbf, const float* __restrict__ ipb,
                       float* __restrict__ accg) {
  __shared__ unsigned short Qs[128 * 64];   // swizzled: idx = i*64 + (d ^ ((i&7)<<3))
  __shared__ unsigned short Ks[128 * 64];
  __shared__ unsigned short Vt[64 * 128];   // idx = d*128 + (j ^ ((d&15)<<3))
  __shared__ unsigned short Ab[128 * 128];  // idx = i*128 + (j ^ ((i&15)<<3))
  __shared__ float accs[143 * 68];
  __shared__ float hth[128];
  __shared__ float bQ[64], bK[64], bV[64];

  const int strip = blockIdx.x, hd = blockIdx.y, v = blockIdx.z;
  const int l0 = strip * SW;
  const int nw = (SW < LWIN - l0) ? SW : (LWIN - l0);
  const int tid = threadIdx.x;

  for (int i = tid; i < 143 * 68; i += 256) accs[i] = 0.0f;
  if (tid < 128) hth[tid] = hannf(tid);
  if (tid < 64) {
    bQ[tid] = ipb[hd * 64 + tid] * 0.125f;
    bK[tid] = ipb[256 + hd * 64 + tid];
    bV[tid] = ipb[512 + hd * 64 + tid];
  }

  const int lane = tid & 63, wv = tid >> 6;
  const int li16 = lane & 15, q4 = lane >> 4;
  const int i0 = wv * 32;

  // per-thread staging coords (loop-invariant)
  const int grp = tid & 7, j00 = tid >> 3;       // Q/K staging
  const int jv = tid & 127, dg0 = tid >> 7;      // V staging

  for (int w = 0; w < nw; ++w) {
    const int l = l0 + w;
    __syncthreads();

    // ---- stage Q (hann*0.125*P + 0.125*bq), K (hann*P + bk) ----
    {
      float4 bq0 = *(float4*)&bQ[grp * 8];
      float4 bq1 = *(float4*)&bQ[grp * 8 + 4];
      float4 bk0 = *(float4*)&bK[grp * 8];
      float4 bk1 = *(float4*)&bK[grp * 8 + 4];
      #pragma unroll
      for (int k = 0; k < 4; ++k) {
        int j = j00 + 32 * k;
        int row = prow(v, l + j);
        float hh = hth[j];
        float hq = hh * 0.125f;
        const uint4* src = (const uint4*)(Pbf + (size_t)row * 768);
        // Q part
        uint4 a = src[hd * 8 + grp];
        uint4 oq;
        oq.x = pk2(hq * bflo(a.x) + bq0.x, hq * bfhi(a.x) + bq0.y);
        oq.y = pk2(hq * bflo(a.y) + bq0.z, hq * bfhi(a.y) + bq0.w);
        oq.z = pk2(hq * bflo(a.z) + bq1.x, hq * bfhi(a.z) + bq1.y);
        oq.w = pk2(hq * bflo(a.w) + bq1.z, hq * bfhi(a.w) + bq1.w);
        *(uint4*)&Qs[j * 64 + ((grp * 8) ^ ((j & 7) << 3))] = oq;
        // K part
        uint4 b = src[32 + hd * 8 + grp];
        uint4 ok;
        ok.x = pk2(hh * bflo(b.x) + bk0.x, hh * bfhi(b.x) + bk0.y);
        ok.y = pk2(hh * bflo(b.y) + bk0.z, hh * bfhi(b.y) + bk0.w);
        ok.z = pk2(hh * bflo(b.z) + bk1.x, hh * bfhi(b.z) + bk1.y);
        ok.w = pk2(hh * bflo(b.w) + bk1.z, hh * bfhi(b.w) + bk1.w);
        *(uint4*)&Ks[j * 64 + ((grp * 8) ^ ((j & 7) << 3))] = ok;
      }
      // ---- stage V transposed (hann*P + bv) ----
      int rowv = prow(v, l + jv);
      float hv = hth[jv];
      const uint4* srcv = (const uint4*)(Pbf + (size_t)rowv * 768);
      #pragma unroll
      for (int k = 0; k < 4; ++k) {
        int dg = dg0 + 2 * k;
        uint4 a = srcv[64 + hd * 8 + dg];
        float4 bv0 = *(float4*)&bV[dg * 8];
        float4 bv1 = *(float4*)&bV[dg * 8 + 4];
        float f0 = hv * bflo(a.x) + bv0.x, f1 = hv * bfhi(a.x) + bv0.y;
        float f2 = hv * bflo(a.y) + bv0.z, f3 = hv * bfhi(a.y) + bv0.w;
        float f4 = hv * bflo(a.z) + bv1.x, f5 = hv * bfhi(a.z) + bv1.y;
        float f6 = hv * bflo(a.w) + bv1.z, f7 = hv * bfhi(a.w) + bv1.w;
        int d = dg * 8;
        Vt[(d + 0) * 128 + (jv ^ (((d + 0) & 15) << 3))] = bfr(f0);
        Vt[(d + 1) * 128 + (jv ^ (((d + 1) & 15) << 3))] = bfr(f1);
        Vt[(d + 2) * 128 + (jv ^ (((d + 2) & 15) << 3))] = bfr(f2);
        Vt[(d + 3) * 128 + (jv ^ (((d + 3) & 15) << 3))] = bfr(f3);
        Vt[(d + 4) * 128 + (jv ^ (((d + 4) & 15) << 3))] = bfr(f4);
        Vt[(d + 5) * 128 + (jv ^ (((d + 5) & 15) << 3))] = bfr(f5);
        Vt[(d + 6) * 128 + (jv ^ (((d + 6) & 15) << 3))] = bfr(f6);
        Vt[(d + 7) * 128 + (jv ^ (((d + 7) & 15) << 3))] = bfr(f7);
      }
    }
    __syncthreads();

    // ---- S^T = K . Q^T  (D[j][i]); A = K rows, B = Q rows ----
    bf16x8 Qf[2][2];
    #pragma unroll
    for (int it = 0; it < 2; ++it)
      #pragma unroll
      for (int ks = 0; ks < 2; ++ks) {
        int i = i0 + 16 * it + li16;
        Qf[it][ks] = *(bf16x8*)&Qs[i * 64 + ((32 * ks + 8 * q4) ^ ((i & 7) << 3))];
      }
    f32x4 S[2][8];
    #pragma unroll
    for (int it = 0; it < 2; ++it)
      #pragma unroll
      for (int tj = 0; tj < 8; ++tj) S[it][tj] = (f32x4){0.f, 0.f, 0.f, 0.f};
    #pragma unroll
    for (int tj = 0; tj < 8; ++tj) {
      #pragma unroll
      for (int ks = 0; ks < 2; ++ks) {
        int jr = 16 * tj + li16;
        bf16x8 Kf = *(bf16x8*)&Ks[jr * 64 + ((32 * ks + 8 * q4) ^ ((jr & 7) << 3))];
        S[0][tj] = __builtin_amdgcn_mfma_f32_16x16x32_bf16(Kf, Qf[0][ks], S[0][tj], 0, 0, 0);
        S[1][tj] = __builtin_amdgcn_mfma_f32_16x16x32_bf16(Kf, Qf[1][ks], S[1][tj], 0, 0, 0);
      }
    }

    // ---- softmax over j (rows of S^T) per i=col; write A to Ab (bf16) ----
    #pragma unroll
    for (int it = 0; it < 2; ++it) {
      float mx = -3.0e38f;
      #pragma unroll
      for (int tj = 0; tj < 8; ++tj)
        #pragma unroll
        for (int r = 0; r < 4; ++r) mx = fmaxf(mx, S[it][tj][r]);
      mx = fmaxf(mx, __shfl_xor(mx, 16));
      mx = fmaxf(mx, __shfl_xor(mx, 32));
      float sum = 0.0f;
      #pragma unroll
      for (int tj = 0; tj < 8; ++tj)
        #pragma unroll
        for (int r = 0; r < 4; ++r) {
          float e = __expf(S[it][tj][r] - mx);
          S[it][tj][r] = e;
          sum += e;
        }
      sum += __shfl_xor(sum, 16);
      sum += __shfl_xor(sum, 32);
      float inv = 1.0f / sum;
      int i = i0 + 16 * it + li16;
      #pragma unroll
      for (int tj = 0; tj < 8; ++tj) {
        uint2 o;
        o.x = pk2(S[it][tj][0] * inv, S[it][tj][1] * inv);
        o.y = pk2(S[it][tj][2] * inv, S[it][tj][3] * inv);
        int jc = 16 * tj + 4 * q4;
        *(uint2*)&Ab[i * 128 + (jc ^ ((i & 15) << 3))] = o;
      }
    }

    // ---- O = A . V  (A rows from Ab, B from Vt) ----
    f32x4 O[2][4];
    #pragma unroll
    for (int it = 0; it < 2; ++it)
      #pragma unroll
      for (int nt = 0; nt < 4; ++nt) O[it][nt] = (f32x4){0.f, 0.f, 0.f, 0.f};
    #pragma unroll
    for (int ks = 0; ks < 4; ++ks) {
      bf16x8 Af[2];
      #pragma unroll
      for (int it = 0; it < 2; ++it) {
        int i = i0 + 16 * it + li16;
        Af[it] = *(bf16x8*)&Ab[i * 128 + ((32 * ks + 8 * q4) ^ ((i & 15) << 3))];
      }
      #pragma unroll
      for (int nt = 0; nt < 4; ++nt) {
        int d = 16 * nt + li16;
        bf16x8 Vf = *(bf16x8*)&Vt[d * 128 + ((32 * ks + 8 * q4) ^ ((d & 15) << 3))];
        O[0][nt] = __builtin_amdgcn_mfma_f32_16x16x32_bf16(Af[0], Vf, O[0][nt], 0, 0, 0);
        O[1][nt] = __builtin_amdgcn_mfma_f32_16x16x32_bf16(Af[1], Vf, O[1][nt], 0, 0, 0);
      }
    }

    // ---- accumulate into strip overlap-add buffer ----
    #pragma unroll
    for (int it = 0; it < 2; ++it)
      #pragma unroll
      for (int nt = 0; nt < 4; ++nt)
        #pragma unroll
        for (int r = 0; r < 4; ++r) {
          int i = i0 + 16 * it + 4 * q4 + r;
          int d = 16 * nt + li16;
          accs[(w + i) * 68 + d] += O[it][nt][r];
        }
  }

  __syncthreads();
  const int span = nw - 1 + 128;
  float* av = accg + (size_t)v * TPAD * CDIM;
  for (int i2 = tid; i2 < span * 64; i2 += 256) {
    int p = i2 >> 6, dd = i2 & 63;
    atomicAdd(&av[(size_t)(l0 + p) * CDIM + hd * 64 + dd], accs[p * 68 + dd]);
  }
}

// ---------------- combine variants + merged projection ----------------
__global__ void k_comb(const float* __restrict__ accg, const float* __restrict__ Mt,
                       const float* __restrict__ vbv, const float* __restrict__ pb,
                       float* __restrict__ z, float* __restrict__ msum) {
  __shared__ float ut[16][257];
  __shared__ float bsc[16];
  int tid = threadIdx.x;
  int s0 = blockIdx.x * 16;
  for (int idx = tid; idx < 16 * 256; idx += 256) {
    int rr = idx >> 8, c = idx & 255;
    int s = s0 + rr;
    int t0 = PADL + s;
    float c0 = countf(t0);
    int s1 = (s + 64) & (TLEN - 1);
    int t1 = PADL + s1;
    float c1 = countf(t1);
    float a0 = accg[(size_t)t0 * CDIM + c];
    float a1 = accg[(size_t)TPAD * CDIM + (size_t)t1 * CDIM + c];
    ut[rr][c] = 0.5f * (a0 / (c0 + 1e-6f) + a1 / (c1 + 1e-6f));
  }
  if (tid < 16) {
    int s = s0 + tid;
    float c0 = countf(PADL + s);
    float c1 = countf(PADL + ((s + 64) & (TLEN - 1)));
    bsc[tid] = 0.5f * (c0 / (c0 + 1e-6f) + c1 / (c1 + 1e-6f));
  }
  __syncthreads();
  float zr[16];
  #pragma unroll
  for (int rr = 0; rr < 16; ++rr) zr[rr] = 0.0f;
  for (int c = 0; c < 256; ++c) {
    float mv = Mt[(size_t)c * CDIM + tid];
    #pragma unroll
    for (int rr = 0; rr < 16; ++rr) zr[rr] += ut[rr][c] * mv;
  }
  float vbe = vbv[tid], pbe = pb[tid];
  float part = 0.0f;
  #pragma unroll
  for (int rr = 0; rr < 16; ++rr) {
    float val = zr[rr] + bsc[rr] * vbe + pbe;
    z[(size_t)(s0 + rr) * CDIM + tid] = val;
    part += val;
  }
  atomicAdd(&msum[tid], part);
}

// ---------------- SE gate ----------------
__global__ void k_se(const float* __restrict__ msum, const float* __restrict__ w1,
                     const float* __restrict__ w2, float* __restrict__ gate) {
  __shared__ float sm[256];
  __shared__ float s1[16];
  int tid = threadIdx.x;
  sm[tid] = msum[tid] * (1.0f / 1024.0f);
  __syncthreads();
  if (tid < 16) {
    float a = 0.0f;
    for (int e = 0; e < 256; ++e) a += sm[e] * w1[(size_t)tid * 256 + e];
    s1[tid] = fmaxf(a, 0.0f);
  }
  __syncthreads();
  float gacc = 0.0f;
  #pragma unroll
  for (int i = 0; i < 16; ++i) gacc += s1[i] * w2[(size_t)tid * 16 + i];
  gate[tid] = 1.0f / (1.0f + __expf(-gacc));
}

// ---------------- out = x + z * gate ----------------
__global__ void k_final(const float* __restrict__ x, const float* __restrict__ z,
                        const float* __restrict__ gate, float* __restrict__ out) {
  int i = blockIdx.x * 256 + threadIdx.x;
  float4 xv = ((const float4*)x)[i];
  float4 zv = ((const float4*)z)[i];
  float4 gv = ((const float4*)gate)[i & 63];
  float4 o;
  o.x = xv.x + zv.x * gv.x;
  o.y = xv.y + zv.y * gv.y;
  o.z = xv.z + zv.z * gv.z;
  o.w = xv.w + zv.w * gv.w;
  ((float4*)out)[i] = o;
}

extern "C" void kernel_launch(void* const* d_in, const int* in_sizes, int n_in,
                              void* d_out, int out_size, void* d_ws, size_t ws_size,
                              hipStream_t stream) {
  const float* x   = (const float*)d_in[0];
  const float* lng = (const float*)d_in[1];
  const float* lnb = (const float*)d_in[2];
  const float* ipw = (const float*)d_in[3];
  const float* ipb = (const float*)d_in[4];
  const float* ow  = (const float*)d_in[5];
  const float* ob  = (const float*)d_in[6];
  const float* pw  = (const float*)d_in[7];
  const float* pb  = (const float*)d_in[8];
  const float* w1  = (const float*)d_in[9];
  const float* w2  = (const float*)d_in[10];
  float* out = (float*)d_out;

  float* ws = (float*)d_ws;
  float* ln = ws;                                    // 262144 f
  unsigned short* Pbf = (unsigned short*)(ln + 262144);  // 1150*768 us = 441600 f
  float* accg = ln + 262144 + 441600;                // 588800 f
  float* Mt   = accg + 588800;                       // 65536
  float* vbv  = Mt + 65536;                          // 256
  float* z    = vbv + 256;                           // 262144
  float* msum = z + 262144;                          // 256
  float* gate = msum + 256;                          // 256

  hipMemsetAsync(Pbf, 0, (size_t)TPAD * 768 * sizeof(unsigned short), stream);
  hipMemsetAsync(accg, 0, (size_t)2 * TPAD * CDIM * sizeof(float), stream);
  hipMemsetAsync(msum, 0, CDIM * sizeof(float), stream);

  k_ln<<<dim3(TLEN / 4), dim3(256), 0, stream>>>(x, lng, lnb, ln);
  k_proj<<<dim3(64, 3), dim3(256), 0, stream>>>(ln, ipw, Pbf);
  k_mmat<<<dim3(256), dim3(256), 0, stream>>>(pw, ow, ob, Mt, vbv);
  k_attn<<<dim3(64, NHEAD, 2), dim3(256), 0, stream>>>(Pbf, ipb, accg);
  k_comb<<<dim3(64), dim3(256), 0, stream>>>(accg, Mt, vbv, pb, z, msum);
  k_se<<<dim3(1), dim3(256), 0, stream>>>(msum, w1, w2, gate);
  k_final<<<dim3(256), dim3(256), 0, stream>>>(x, z, gate, out);
}

// Round 3
// 273.894 us; speedup vs baseline: 6.7124x; 1.2649x over previous
//
#include <hip/hip_runtime.h>

#define TLEN 1024
#define CDIM 256
#define NHEAD 4
#define HD 64
#define WIN_ 128
#define PADL 63
#define LWIN 1023
#define TPAD 1150
#define SW 32        // windows per strip: 32 strips x 4 heads x 2 variants = 256 blocks

typedef __attribute__((ext_vector_type(8))) short bf16x8;
typedef __attribute__((ext_vector_type(4))) float f32x4;

__device__ __forceinline__ int prow(int v, int t) {
  if (v == 0) return t;
  if (t < PADL || t >= PADL + TLEN) return t;
  int s = t - PADL;
  s = (s + (TLEN - 64)) & (TLEN - 1);   // roll(x, +64)
  return PADL + s;
}

__device__ __forceinline__ float hannf(int j) {
  return 0.5f * (1.0f - __cosf(6.283185307179586f * (float)j / 127.0f));
}

__device__ __forceinline__ float countf(int t) {
  int lo = t - 127; if (lo < 0) lo = 0;
  int hi = t;       if (hi > LWIN - 1) hi = LWIN - 1;
  return (float)(hi - lo + 1);
}

__device__ __forceinline__ unsigned short bfr(float f) {  // fp32 -> bf16 RTNE
  unsigned int u = __float_as_uint(f);
  u += 0x7FFFu + ((u >> 16) & 1u);
  return (unsigned short)(u >> 16);
}
__device__ __forceinline__ unsigned int pk2(float a, float b) {
  return (unsigned int)bfr(a) | ((unsigned int)bfr(b) << 16);
}
__device__ __forceinline__ float bfu(unsigned short u) {
  return __uint_as_float(((unsigned int)u) << 16);
}

// ---------------- LayerNorm ----------------
__global__ void k_ln(const float* __restrict__ x, const float* __restrict__ g,
                     const float* __restrict__ b, float* __restrict__ ln) {
  int wv = threadIdx.x >> 6, lane = threadIdx.x & 63;
  int r = blockIdx.x * 4 + wv;
  float4 v = ((const float4*)(x + (size_t)r * CDIM))[lane];
  float s = v.x + v.y + v.z + v.w;
  float q = v.x * v.x + v.y * v.y + v.z * v.z + v.w * v.w;
  #pragma unroll
  for (int m = 32; m >= 1; m >>= 1) { s += __shfl_xor(s, m); q += __shfl_xor(q, m); }
  float mu = s * (1.0f / 256.0f);
  float var = q * (1.0f / 256.0f) - mu * mu;
  float rs = rsqrtf(var + 1e-5f);
  float4 gg = ((const float4*)g)[lane];
  float4 bb = ((const float4*)b)[lane];
  float4 o;
  o.x = (v.x - mu) * rs * gg.x + bb.x;
  o.y = (v.y - mu) * rs * gg.y + bb.y;
  o.z = (v.z - mu) * rs * gg.z + bb.z;
  o.w = (v.w - mu) * rs * gg.w + bb.w;
  ((float4*)(ln + (size_t)r * CDIM))[lane] = o;
}

// ---------------- P projection (bf16 out) ----------------
__global__ void k_proj(const float* __restrict__ ln, const float* __restrict__ W,
                       unsigned short* __restrict__ Pbf) {
  __shared__ float lnt[16][257];
  __shared__ float Wt[256][65];
  int tid = threadIdx.x;
  int s0 = blockIdx.x * 16;
  int e0 = blockIdx.y * 256;
  for (int idx = tid; idx < 16 * 256; idx += 256)
    lnt[idx >> 8][idx & 255] = ln[(size_t)(s0 + (idx >> 8)) * CDIM + (idx & 255)];
  float acc[16];
  #pragma unroll
  for (int r = 0; r < 16; ++r) acc[r] = 0.0f;
  for (int kk = 0; kk < 4; ++kk) {
    __syncthreads();
    for (int idx = tid; idx < 256 * 64; idx += 256)
      Wt[idx >> 6][idx & 63] = W[(size_t)(e0 + (idx >> 6)) * CDIM + kk * 64 + (idx & 63)];
    __syncthreads();
    for (int c = 0; c < 64; ++c) {
      float wv = Wt[tid][c];
      #pragma unroll
      for (int r = 0; r < 16; ++r) acc[r] += lnt[r][kk * 64 + c] * wv;
    }
  }
  #pragma unroll
  for (int r = 0; r < 16; ++r)
    Pbf[(size_t)(PADL + s0 + r) * 768 + e0 + tid] = bfr(acc[r]);
}

// ---------------- merged out/proj matrices ----------------
__global__ void k_mmat(const float* __restrict__ pw, const float* __restrict__ ow,
                       const float* __restrict__ ob, float* __restrict__ Mt,
                       float* __restrict__ vbv) {
  __shared__ float pr[256];
  __shared__ float red[256];
  int e = blockIdx.x, tid = threadIdx.x;
  pr[tid] = pw[(size_t)e * CDIM + tid];
  __syncthreads();
  float acc = 0.0f;
  for (int m = 0; m < 256; ++m) acc += pr[m] * ow[(size_t)m * CDIM + tid];
  Mt[(size_t)tid * CDIM + e] = acc;
  red[tid] = pr[tid] * ob[tid];
  __syncthreads();
  for (int s = 128; s > 0; s >>= 1) { if (tid < s) red[tid] += red[tid + s]; __syncthreads(); }
  if (tid == 0) vbv[e] = red[0];
}

// ---------------- V window staging: global -> LDS transposed ----------------
__device__ __forceinline__ void stage_v(const unsigned short* __restrict__ Pbf,
                                        unsigned short* vt, int v, int hd,
                                        int trow0, int tid) {
  int j = tid & 127, dgsel = tid >> 7;
  int row = prow(v, trow0 + j);
  const unsigned short* base = Pbf + (size_t)row * 768 + 512 + hd * 64;
  #pragma unroll
  for (int pass = 0; pass < 2; ++pass) {
    int dg = dgsel + 4 * pass;
    uint4 a = *(const uint4*)(base + dg * 8);
    int d0 = dg * 8;
    vt[(d0 + 0) * 128 + (j ^ 0)]  = (unsigned short)(a.x & 0xFFFF);
    vt[(d0 + 1) * 128 + (j ^ 8)]  = (unsigned short)(a.x >> 16);
    vt[(d0 + 2) * 128 + (j ^ 16)] = (unsigned short)(a.y & 0xFFFF);
    vt[(d0 + 3) * 128 + (j ^ 24)] = (unsigned short)(a.y >> 16);
    vt[(d0 + 4) * 128 + (j ^ 32)] = (unsigned short)(a.z & 0xFFFF);
    vt[(d0 + 5) * 128 + (j ^ 40)] = (unsigned short)(a.z >> 16);
    vt[(d0 + 6) * 128 + (j ^ 48)] = (unsigned short)(a.w & 0xFFFF);
    vt[(d0 + 7) * 128 + (j ^ 56)] = (unsigned short)(a.w >> 16);
  }
}

// ---------------- MFMA attention, strip-span formulation ----------------
__launch_bounds__(512, 2)
__global__ void k_attn(const unsigned short* __restrict__ Pbf, const float* __restrict__ ipb,
                       float* __restrict__ accg) {
  __shared__ __align__(16) unsigned short Pq[159 * 64];   // raw Q-proj span, swizzle d^((t&7)<<3)
  __shared__ __align__(16) unsigned short Pk[159 * 64];
  __shared__ __align__(16) unsigned short Vt[2][64 * 128]; // V^T window, swizzle j^((d&7)<<3)
  __shared__ __align__(16) unsigned short Ab[128 * 128];   // A' window, swizzle j^((i&7)<<3)
  __shared__ float accs[159 * 65];
  __shared__ float hth[128];
  __shared__ float aA[160], bB[160];
  __shared__ float bqS[64], bkS[64];
  __shared__ float cS;

  const int strip = blockIdx.x, hd = blockIdx.y, v = blockIdx.z;
  const int l0 = strip * SW;
  const int nw = (SW < LWIN - l0) ? SW : (LWIN - l0);
  const int span = nw - 1 + WIN_;
  const int tid = threadIdx.x;
  const int lane = tid & 63, wv = tid >> 6;
  const int li16 = lane & 15, q4 = lane >> 4;
  const int iw = 16 * wv + li16;          // this thread's output row i (window-local)

  for (int i = tid; i < 159 * 65; i += 512) accs[i] = 0.0f;
  if (tid < 128) hth[tid] = hannf(tid);
  if (tid < 64) {
    bqS[tid] = ipb[hd * 64 + tid];
    bkS[tid] = ipb[256 + hd * 64 + tid];
  }
  // stage raw Pq/Pk spans
  for (int i = tid; i < span * 8; i += 512) {
    int t = i >> 3, dg = i & 7;
    int row = prow(v, l0 + t);
    const unsigned short* src = Pbf + (size_t)row * 768 + hd * 64;
    uint4 q = *(const uint4*)(src + dg * 8);
    uint4 k = *(const uint4*)(src + 256 + dg * 8);
    int off = (dg * 8) ^ ((t & 7) << 3);
    *(uint4*)&Pq[t * 64 + off] = q;
    *(uint4*)&Pk[t * 64 + off] = k;
  }
  __syncthreads();

  // bias-dot arrays a(t)=Pq(t).bk, b(t)=bq.Pk(t); scalar c=bq.bk
  for (int p = tid; p < span; p += 512) {
    float a = 0.0f, b = 0.0f;
    int sw = (p & 7) << 3;
    for (int d = 0; d < 64; ++d) {
      int off = d ^ sw;
      a += bfu(Pq[p * 64 + off]) * bkS[d];
      b += bqS[d] * bfu(Pk[p * 64 + off]);
    }
    aA[p] = a; bB[p] = b;
  }
  if (tid == 0) {
    float c = 0.0f;
    for (int d = 0; d < 64; ++d) c += bqS[d] * bkS[d];
    cS = c;
  }
  stage_v(Pbf, &Vt[0][0], v, hd, l0, tid);
  __syncthreads();

  // per-thread hann registers: hj8[m] = h(j)/8 at j = 16*(m>>2) + 4*q4 + (m&3)
  float hj8[32];
  #pragma unroll
  for (int tj = 0; tj < 8; ++tj)
    #pragma unroll
    for (int r = 0; r < 4; ++r) hj8[tj * 4 + r] = hth[16 * tj + 4 * q4 + r] * 0.125f;
  const float h_i = hth[iw];
  const float hq_i = h_i * 0.125f;
  const float c_s = cS;

  #pragma unroll 1
  for (int w = 0; w < nw; ++w) {
    // ---- S^T[j][i] = sum_d Pk[w+j][d] * Pq[w+i][d]  (raw Gram) ----
    bf16x8 Qf[2];
    {
      int t = w + iw, sw = (t & 7) << 3;
      Qf[0] = *(bf16x8*)&Pq[t * 64 + (0  ^ sw) + 8 * q4];
      Qf[1] = *(bf16x8*)&Pq[t * 64 + (32 ^ sw) + 8 * q4];
    }
    f32x4 S[8];
    #pragma unroll
    for (int tj = 0; tj < 8; ++tj) S[tj] = (f32x4){0.f, 0.f, 0.f, 0.f};
    #pragma unroll
    for (int tj = 0; tj < 8; ++tj) {
      int t = w + 16 * tj + li16, sw = (t & 7) << 3;
      bf16x8 Kf0 = *(bf16x8*)&Pk[t * 64 + (0  ^ sw) + 8 * q4];
      bf16x8 Kf1 = *(bf16x8*)&Pk[t * 64 + (32 ^ sw) + 8 * q4];
      S[tj] = __builtin_amdgcn_mfma_f32_16x16x32_bf16(Kf0, Qf[0], S[tj], 0, 0, 0);
      S[tj] = __builtin_amdgcn_mfma_f32_16x16x32_bf16(Kf1, Qf[1], S[tj], 0, 0, 0);
    }

    // ---- corrections + softmax over j ----
    const float cc_i = fmaf(hq_i, aA[w + iw], 0.125f * c_s);
    float mx = -3.0e38f;
    #pragma unroll
    for (int tj = 0; tj < 8; ++tj)
      #pragma unroll
      for (int r = 0; r < 4; ++r) {
        int j = 16 * tj + 4 * q4 + r;
        float s = fmaf(hj8[tj * 4 + r], fmaf(h_i, S[tj][r], bB[w + j]), cc_i);
        S[tj][r] = s;
        mx = fmaxf(mx, s);
      }
    mx = fmaxf(mx, __shfl_xor(mx, 16));
    mx = fmaxf(mx, __shfl_xor(mx, 32));
    float sum = 0.0f;
    #pragma unroll
    for (int tj = 0; tj < 8; ++tj)
      #pragma unroll
      for (int r = 0; r < 4; ++r) {
        float e = __expf(S[tj][r] - mx);
        S[tj][r] = e;
        sum += e;
      }
    sum += __shfl_xor(sum, 16);
    sum += __shfl_xor(sum, 32);
    const float inv8 = 8.0f / sum;   // recovers h(j) from hj8

    // ---- A'[i][j] = softmax * h(j), bf16 into Ab (wave-private rows) ----
    {
      int sw = (iw & 7) << 3;
      #pragma unroll
      for (int tj = 0; tj < 8; ++tj) {
        uint2 o;
        o.x = pk2(S[tj][0] * inv8 * hj8[tj * 4 + 0], S[tj][1] * inv8 * hj8[tj * 4 + 1]);
        o.y = pk2(S[tj][2] * inv8 * hj8[tj * 4 + 2], S[tj][3] * inv8 * hj8[tj * 4 + 3]);
        *(uint2*)&Ab[iw * 128 + ((16 * tj + 4 * q4) ^ sw)] = o;
      }
    }

    // ---- O^T[d][i] = sum_j Vt[d][j] * A'[i][j] ----
    f32x4 O[4];
    #pragma unroll
    for (int mt = 0; mt < 4; ++mt) O[mt] = (f32x4){0.f, 0.f, 0.f, 0.f};
    const unsigned short* vt = &Vt[w & 1][0];
    {
      int swi = (iw & 7) << 3;
      #pragma unroll
      for (int ks = 0; ks < 4; ++ks) {
        bf16x8 Bf = *(bf16x8*)&Ab[iw * 128 + ((32 * ks + 8 * q4) ^ swi)];
        #pragma unroll
        for (int mt = 0; mt < 4; ++mt) {
          int d = 16 * mt + li16;
          bf16x8 Af = *(bf16x8*)&vt[d * 128 + ((32 * ks + 8 * q4) ^ ((d & 7) << 3))];
          O[mt] = __builtin_amdgcn_mfma_f32_16x16x32_bf16(Af, Bf, O[mt], 0, 0, 0);
        }
      }
    }

    // ---- accumulate O^T into strip overlap-add buffer ----
    {
      int p = w + iw;
      #pragma unroll
      for (int mt = 0; mt < 4; ++mt)
        #pragma unroll
        for (int r = 0; r < 4; ++r)
          accs[p * 65 + 16 * mt + 4 * q4 + r] += O[mt][r];
    }

    if (w + 1 < nw) stage_v(Pbf, &Vt[(w + 1) & 1][0], v, hd, l0 + w + 1, tid);
    __syncthreads();
  }

  // ---- epilogue: + cnt*bv, atomic into global ----
  float* av = accg + (size_t)v * TPAD * CDIM;
  for (int i = tid; i < span * 64; i += 512) {
    int p = i >> 6, dd = i & 63;
    int lo = p - 127; if (lo < 0) lo = 0;
    int hi = p; if (hi > nw - 1) hi = nw - 1;
    float cnt = (float)(hi - lo + 1);
    float bvd = ipb[512 + hd * 64 + dd];
    atomicAdd(&av[(size_t)(l0 + p) * CDIM + hd * 64 + dd],
              accs[p * 65 + dd] + cnt * bvd);
  }
}

// ---------------- combine variants + merged projection ----------------
__global__ void k_comb(const float* __restrict__ accg, const float* __restrict__ Mt,
                       const float* __restrict__ vbv, const float* __restrict__ pb,
                       float* __restrict__ z, float* __restrict__ msum) {
  __shared__ float ut[4][257];
  __shared__ float bsc[4];
  int tid = threadIdx.x;
  int s0 = blockIdx.x * 4;
  for (int idx = tid; idx < 4 * 256; idx += 256) {
    int rr = idx >> 8, c = idx & 255;
    int s = s0 + rr;
    int t0 = PADL + s;
    float c0 = countf(t0);
    int s1 = (s + 64) & (TLEN - 1);
    int t1 = PADL + s1;
    float c1 = countf(t1);
    float a0 = accg[(size_t)t0 * CDIM + c];
    float a1 = accg[(size_t)TPAD * CDIM + (size_t)t1 * CDIM + c];
    ut[rr][c] = 0.5f * (a0 / (c0 + 1e-6f) + a1 / (c1 + 1e-6f));
  }
  if (tid < 4) {
    int s = s0 + tid;
    float c0 = countf(PADL + s);
    float c1 = countf(PADL + ((s + 64) & (TLEN - 1)));
    bsc[tid] = 0.5f * (c0 / (c0 + 1e-6f) + c1 / (c1 + 1e-6f));
  }
  __syncthreads();
  float zr[4];
  #pragma unroll
  for (int rr = 0; rr < 4; ++rr) zr[rr] = 0.0f;
  for (int c = 0; c < 256; ++c) {
    float mv = Mt[(size_t)c * CDIM + tid];
    #pragma unroll
    for (int rr = 0; rr < 4; ++rr) zr[rr] += ut[rr][c] * mv;
  }
  float vbe = vbv[tid], pbe = pb[tid];
  float part = 0.0f;
  #pragma unroll
  for (int rr = 0; rr < 4; ++rr) {
    float val = zr[rr] + bsc[rr] * vbe + pbe;
    z[(size_t)(s0 + rr) * CDIM + tid] = val;
    part += val;
  }
  atomicAdd(&msum[tid], part);
}

// ---------------- SE gate ----------------
__global__ void k_se(const float* __restrict__ msum, const float* __restrict__ w1,
                     const float* __restrict__ w2, float* __restrict__ gate) {
  __shared__ float sm[256];
  __shared__ float s1[16];
  int tid = threadIdx.x;
  sm[tid] = msum[tid] * (1.0f / 1024.0f);
  __syncthreads();
  if (tid < 16) {
    float a = 0.0f;
    for (int e = 0; e < 256; ++e) a += sm[e] * w1[(size_t)tid * 256 + e];
    s1[tid] = fmaxf(a, 0.0f);
  }
  __syncthreads();
  float gacc = 0.0f;
  #pragma unroll
  for (int i = 0; i < 16; ++i) gacc += s1[i] * w2[(size_t)tid * 16 + i];
  gate[tid] = 1.0f / (1.0f + __expf(-gacc));
}

// ---------------- out = x + z * gate ----------------
__global__ void k_final(const float* __restrict__ x, const float* __restrict__ z,
                        const float* __restrict__ gate, float* __restrict__ out) {
  int i = blockIdx.x * 256 + threadIdx.x;
  float4 xv = ((const float4*)x)[i];
  float4 zv = ((const float4*)z)[i];
  float4 gv = ((const float4*)gate)[i & 63];
  float4 o;
  o.x = xv.x + zv.x * gv.x;
  o.y = xv.y + zv.y * gv.y;
  o.z = xv.z + zv.z * gv.z;
  o.w = xv.w + zv.w * gv.w;
  ((float4*)out)[i] = o;
}

extern "C" void kernel_launch(void* const* d_in, const int* in_sizes, int n_in,
                              void* d_out, int out_size, void* d_ws, size_t ws_size,
                              hipStream_t stream) {
  const float* x   = (const float*)d_in[0];
  const float* lng = (const float*)d_in[1];
  const float* lnb = (const float*)d_in[2];
  const float* ipw = (const float*)d_in[3];
  const float* ipb = (const float*)d_in[4];
  const float* ow  = (const float*)d_in[5];
  const float* ob  = (const float*)d_in[6];
  const float* pw  = (const float*)d_in[7];
  const float* pb  = (const float*)d_in[8];
  const float* w1  = (const float*)d_in[9];
  const float* w2  = (const float*)d_in[10];
  float* out = (float*)d_out;

  float* ws = (float*)d_ws;
  float* ln = ws;                                        // 262144 f
  unsigned short* Pbf = (unsigned short*)(ln + 262144);  // 1150*768 bf16 = 441600 f-slots
  float* accg = ln + 262144 + 441600;                    // 2*1150*256 = 588800 f
  float* Mt   = accg + 588800;                           // 65536
  float* vbv  = Mt + 65536;                              // 256
  float* z    = vbv + 256;                               // 262144
  float* msum = z + 262144;                              // 256
  float* gate = msum + 256;                              // 256

  hipMemsetAsync(Pbf, 0, (size_t)TPAD * 768 * sizeof(unsigned short), stream);
  hipMemsetAsync(accg, 0, (size_t)2 * TPAD * CDIM * sizeof(float), stream);
  hipMemsetAsync(msum, 0, CDIM * sizeof(float), stream);

  k_ln<<<dim3(TLEN / 4), dim3(256), 0, stream>>>(x, lng, lnb, ln);
  k_proj<<<dim3(64, 3), dim3(256), 0, stream>>>(ln, ipw, Pbf);
  k_mmat<<<dim3(256), dim3(256), 0, stream>>>(pw, ow, ob, Mt, vbv);
  k_attn<<<dim3(32, NHEAD, 2), dim3(512), 0, stream>>>(Pbf, ipb, accg);
  k_comb<<<dim3(256), dim3(256), 0, stream>>>(accg, Mt, vbv, pb, z, msum);
  k_se<<<dim3(1), dim3(256), 0, stream>>>(msum, w1, w2, gate);
  k_final<<<dim3(256), dim3(256), 0, stream>>>(x, z, gate, out);
}